// Round 16
// baseline (483.596 us; speedup 1.0000x reference)
//
#include <hip/hip_runtime.h>

#define N_NODES 50000
#define N_EDGES 800000
#define NUM_GRAPHS 128
#define EPS 1e-5f
#define SCAN_BLOCKS 196          // ceil(50000/256)
#define NPAD 50048               // 391 * 128 (row-tile padded node count)
#define POOL_SPLITS 16
#define INV_N (1.0f / 50000.0f)
#define NSLICE 8
#define SLICE_SZ 6250            // N_NODES / NSLICE
#define FILL_CHUNKS 256
#define FILL_CHUNK 3125          // N_EDGES / FILL_CHUNKS

typedef __attribute__((ext_vector_type(8))) short short8;
typedef __attribute__((ext_vector_type(4))) float floatx4;
typedef __attribute__((ext_vector_type(4))) unsigned short ushort4v;

__device__ __forceinline__ unsigned short f2bf_rne(float f) {
    unsigned int u = __float_as_uint(f);
    u += 0x7FFF + ((u >> 16) & 1);
    return (unsigned short)(u >> 16);
}
__device__ __forceinline__ float bf2f(unsigned short h) {
    return __uint_as_float(((unsigned int)h) << 16);
}
__device__ __forceinline__ float bflo(unsigned int u) { return __uint_as_float(u << 16); }
__device__ __forceinline__ float bfhi(unsigned int u) {
    return __uint_as_float(u & 0xFFFF0000u);
}

// async global->LDS, 16B per lane
__device__ __forceinline__ void gload16(const void* g, void* l) {
#if __has_builtin(__builtin_amdgcn_global_load_lds)
    __builtin_amdgcn_global_load_lds(
        reinterpret_cast<const __attribute__((address_space(1))) unsigned int*>(
            reinterpret_cast<unsigned long long>(g)),
        reinterpret_cast<__attribute__((address_space(3))) unsigned int*>(
            reinterpret_cast<unsigned long long>(l)),
        16, 0, 0);
#else
    *(uint4*)l = *(const uint4*)g;
#endif
}

// ---------------- fused zero (deg ints + stats/pool floats) ----------------

__global__ void zero_all_kernel(int* deg, float* f, int nInt, int nF) {
    int i = blockIdx.x * blockDim.x + threadIdx.x;
    if (i < nInt) deg[i] = 0;
    if (i < nF) f[i] = 0.0f;
}

// ---------------- W packing helper (bf16 only, fragment order) ----------------

__device__ __forceinline__ void wpack_one(const float* __restrict__ W, short* __restrict__ Wf,
                                          int K, int M, int t) {
    int KT = K >> 5, MT = M >> 4;
    if (t >= KT * MT * 64) return;
    int lane = t & 63, chunk = t >> 6;
    int kt = chunk / MT, nt = chunk % MT;
    int q = lane >> 4, m = lane & 15;
    int n = nt * 16 + m;
    short* op = Wf + ((size_t)(kt * MT + nt)) * 512 + lane * 8;
#pragma unroll
    for (int j = 0; j < 8; ++j)
        op[j] = (short)f2bf_rne(W[(size_t)(kt * 32 + q * 8 + j) * M + n]);
}

// ---------------- fused prologue: count_deg+rank | wpack x3 | x->bf16 ----------

__global__ __launch_bounds__(256) void prologue_kernel(
        const int* __restrict__ dst, int* deg, int* __restrict__ rank,
        const float* __restrict__ x, unsigned short* __restrict__ xbf,
        const float* __restrict__ W1, const float* __restrict__ W2,
        const float* __restrict__ W3, short* W1f, short* W2f, short* W3f) {
    int b = blockIdx.x;
    if (b < 2048) {
        int i = b * 256 + threadIdx.x;
        const int stride = 2048 * 256;
        for (; i < N_EDGES; i += stride) rank[i] = atomicAdd(&deg[dst[i]], 1);
    } else if (b < 2112) {
        int bb = b - 2048;
        if (bb < 16) wpack_one(W1, W1f, 128, 256, bb * 256 + threadIdx.x);
        else if (bb < 48) wpack_one(W2, W2f, 256, 256, (bb - 16) * 256 + threadIdx.x);
        else wpack_one(W3, W3f, 256, 128, (bb - 48) * 256 + threadIdx.x);
    } else {
        const int n4 = N_NODES * 128 / 4;
        int i = (b - 2112) * 256 + threadIdx.x;
        const int stride = 1984 * 256;
        for (; i < n4; i += stride) {
            float4 v = ((const float4*)x)[i];
            ushort4v o = {f2bf_rne(v.x), f2bf_rne(v.y), f2bf_rne(v.z), f2bf_rne(v.w)};
            ((ushort4v*)xbf)[i] = o;
        }
    }
}

// ---------------- scan phases ----------------

__global__ __launch_bounds__(256) void scan_p1_kernel(const int* __restrict__ deg,
                                                      int* __restrict__ partial, int n) {
    __shared__ int red[256];
    int tid = threadIdx.x;
    int i = blockIdx.x * 256 + tid;
    red[tid] = (i < n) ? deg[i] : 0;
    __syncthreads();
#pragma unroll
    for (int s = 128; s > 0; s >>= 1) {
        if (tid < s) red[tid] += red[tid + s];
        __syncthreads();
    }
    if (tid == 0) partial[blockIdx.x] = red[0];
}

// block 0: exclusive scan of block partials; block 1: graph bounds (fused)
__global__ __launch_bounds__(256) void scan_p2_bounds_kernel(
        const int* __restrict__ partial, int* __restrict__ block_off,
        int* __restrict__ row_start, const int* __restrict__ batch,
        int* __restrict__ gstart, int nb, int n, int E) {
    if (blockIdx.x == 1) {
        int g = threadIdx.x;
        if (g > NUM_GRAPHS) return;
        int lo = 0, hi = n;
        while (lo < hi) {
            int mid = (lo + hi) >> 1;
            if (batch[mid] < g) lo = mid + 1; else hi = mid;
        }
        gstart[g] = lo;
        return;
    }
    __shared__ int s[256];
    int tid = threadIdx.x;
    int v = (tid < nb) ? partial[tid] : 0;
    s[tid] = v;
    __syncthreads();
#pragma unroll
    for (int off = 1; off < 256; off <<= 1) {
        int t = (tid >= off) ? s[tid - off] : 0;
        __syncthreads();
        s[tid] += t;
        __syncthreads();
    }
    if (tid < nb) block_off[tid] = s[tid] - v;
    if (tid == 0) row_start[n] = E;
}

// exclusive scan -> row_start; also dinv = rsqrt(deg+1) (fused)
__global__ __launch_bounds__(256) void scan_p3_kernel(const int* __restrict__ deg,
                                                      const int* __restrict__ block_off,
                                                      int* __restrict__ row_start,
                                                      float* __restrict__ dinv, int n) {
    __shared__ int s[256];
    int tid = threadIdx.x;
    int i = blockIdx.x * 256 + tid;
    int v = (i < n) ? deg[i] : 0;
    s[tid] = v;
    __syncthreads();
#pragma unroll
    for (int off = 1; off < 256; off <<= 1) {
        int t = (tid >= off) ? s[tid - off] : 0;
        __syncthreads();
        s[tid] += t;
        __syncthreads();
    }
    if (i < n) {
        row_start[i] = block_off[blockIdx.x] + s[tid] - v;
        dinv[i] = rsqrtf((float)(v + 1));
    }
}

// XCD-sliced fill; also stores csr_w = dinv[src] per edge.
__global__ __launch_bounds__(256) void fill_csr_kernel(
        const int* __restrict__ src, const int* __restrict__ dst,
        const int* __restrict__ rank, const int* __restrict__ row_start,
        const float* __restrict__ dinv, int* __restrict__ csr_src,
        float* __restrict__ csr_w, int E) {
    int s = blockIdx.x & (NSLICE - 1);
    int c = blockIdx.x >> 3;
    int lo = s * SLICE_SZ;
    int hi = lo + SLICE_SZ;
    int base = c * FILL_CHUNK;
    int end = min(E, base + FILL_CHUNK);
    for (int i = base + threadIdx.x; i < end; i += 256) {
        int d = dst[i];
        if (d >= lo && d < hi) {
            int sv = src[i];
            int p = row_start[d] + rank[i];
            csr_src[p] = sv;
            csr_w[p] = dinv[sv];
        }
    }
}

// ---------------- BN finalize (inline helper) ----------------

__device__ __forceinline__ void bn_coeff(const float* __restrict__ sums,
                                         const float* __restrict__ sumsq,
                                         const float* __restrict__ gamma,
                                         const float* __restrict__ beta, int c,
                                         float& sc, float& sh) {
    float mu = sums[c] * INV_N;
    float var = sumsq[c] * INV_N - mu * mu;
    float rs = rsqrtf(var + EPS);
    sc = gamma[c] * rs;
    sh = beta[c] - mu * sc;
}

// ---------------- plain double-buffered LDS MFMA GEMM (bf16 W) ----------------
// POUT: panel-major output (for next GEMM), else row-major (for gather).

template <int KT, bool POUT>
__global__ __launch_bounds__(256) void gemm_lds_kernel(
        const unsigned short* __restrict__ Ap, const short* __restrict__ Wf,
        const float* __restrict__ bias, unsigned short* __restrict__ Hout, int N, int M) {
    const int MT = M >> 4;
    __shared__ unsigned short sA[2][128 * 32];   // 2 x 8 KB
    __shared__ short sW[2][8 * 512];             // 2 x 8 KB
    int tid = threadIdx.x;
    int wave = tid >> 6, lane = tid & 63;
    int wr = wave >> 1, wc = wave & 1;
    int bm = blockIdx.x * 128;
    int bn = blockIdx.y * 128;
    int ntbb = bn >> 4;
    int q = lane >> 4, l16 = lane & 15;
    floatx4 acc[4][4] = {};

    auto stage = [&](int kt, int p) {
        const char* ab = (const char*)(Ap + ((size_t)kt * NPAD + bm) * 32);
        const char* wb = (const char*)(Wf + (size_t)(kt * MT + ntbb) * 512);
        char* sa = (char*)sA[p];
        char* sw = (char*)sW[p];
        gload16(ab + tid * 16, sa + tid * 16);
        gload16(ab + (256 + tid) * 16, sa + (256 + tid) * 16);
#pragma unroll
        for (int i = 0; i < 2; ++i)
            gload16(wb + (i * 256 + tid) * 16, sw + (i * 256 + tid) * 16);
    };

    stage(0, 0);
    int p = 0;
    for (int kt = 0; kt < KT; ++kt) {
        __syncthreads();
        if (kt + 1 < KT) stage(kt + 1, p ^ 1);
        short8 a[4], wv[4];
#pragma unroll
        for (int mt = 0; mt < 4; ++mt)
            a[mt] = *(const short8*)&sA[p][(wr * 64 + mt * 16 + l16) * 32 + q * 8];
#pragma unroll
        for (int nt = 0; nt < 4; ++nt)
            wv[nt] = *(const short8*)&sW[p][(wc * 4 + nt) * 512 + lane * 8];
#pragma unroll
        for (int nt = 0; nt < 4; ++nt)
#pragma unroll
            for (int mt = 0; mt < 4; ++mt)
                acc[mt][nt] = __builtin_amdgcn_mfma_f32_16x16x32_bf16(a[mt], wv[nt],
                                                                      acc[mt][nt], 0, 0, 0);
        p ^= 1;
    }
#pragma unroll
    for (int nt = 0; nt < 4; ++nt) {
        int col = bn + wc * 64 + nt * 16 + l16;
        float bv = bias ? bias[col] : 0.0f;
#pragma unroll
        for (int mt = 0; mt < 4; ++mt) {
#pragma unroll
            for (int r = 0; r < 4; ++r) {
                int row = bm + wr * 64 + mt * 16 + q * 4 + r;
                if (row < N) {
                    unsigned short v = f2bf_rne(acc[mt][nt][r] + bv);
                    if constexpr (POUT)
                        Hout[((size_t)(col >> 5) * NPAD + row) * 32 + (col & 31)] = v;
                    else
                        Hout[(size_t)row * M + col] = v;
                }
            }
        }
    }
}

// ---------------- BN-fused GEMM: H = relu(bn(A)) @ W, row-major bf16 out ---------

template <int KT>
__global__ __launch_bounds__(256) void gemm_bn_lds_kernel(
        const unsigned short* __restrict__ Abuf, const float* __restrict__ sums,
        const float* __restrict__ sumsq, const float* __restrict__ gamma,
        const float* __restrict__ beta, const short* __restrict__ Wf,
        unsigned short* __restrict__ Hout, int N, int M) {
    const int MT = M >> 4;
    __shared__ unsigned short sA[2][128 * 32];   // 2 x 8 KB
    __shared__ short sW[2][8 * 512];             // 2 x 8 KB
    __shared__ float scs[KT * 32], shs[KT * 32]; // 2 KB
    int tid = threadIdx.x;
    int wave = tid >> 6, lane = tid & 63;
    int wr = wave >> 1, wc = wave & 1;
    int bm = blockIdx.x * 128;
    int bn = blockIdx.y * 128;
    int ntbb = bn >> 4;
    int q = lane >> 4, l16 = lane & 15;

    if (tid < KT * 32) {
        float sc, sh;
        bn_coeff(sums, sumsq, gamma, beta, tid, sc, sh);
        scs[tid] = sc;
        shs[tid] = sh;
    }
    __syncthreads();

    int arow = tid >> 1;          // 0..127 (tile row)
    int acb = (tid & 1) * 16;     // channel base within 32-panel

    auto stageW = [&](int kt, int p) {
        const char* wb = (const char*)(Wf + (size_t)(kt * MT + ntbb) * 512);
        char* sw = (char*)sW[p];
#pragma unroll
        for (int i = 0; i < 2; ++i)
            gload16(wb + (i * 256 + tid) * 16, sw + (i * 256 + tid) * 16);
    };
    auto loadA = [&](int kt, uint4& r0, uint4& r1) {
        const unsigned short* ptr = Abuf + ((size_t)kt * NPAD + bm + arow) * 32 + acb;
        r0 = *(const uint4*)ptr;
        r1 = *(const uint4*)(ptr + 8);
    };
    auto xformA = [&](int kt, uint4 r0, uint4 r1, int p) {
        unsigned int in[8] = {r0.x, r0.y, r0.z, r0.w, r1.x, r1.y, r1.z, r1.w};
        unsigned int ow[8];
#pragma unroll
        for (int u = 0; u < 8; ++u) {
            int cb = kt * 32 + acb + 2 * u;
            float a = fmaxf(bflo(in[u]) * scs[cb] + shs[cb], 0.0f);
            float b = fmaxf(bfhi(in[u]) * scs[cb + 1] + shs[cb + 1], 0.0f);
            ow[u] = (unsigned int)f2bf_rne(a) | ((unsigned int)f2bf_rne(b) << 16);
        }
        uint4* d = (uint4*)&sA[p][(size_t)arow * 32 + acb];
        d[0] = make_uint4(ow[0], ow[1], ow[2], ow[3]);
        d[1] = make_uint4(ow[4], ow[5], ow[6], ow[7]);
    };

    floatx4 acc[4][4] = {};
    uint4 a0, a1;
    stageW(0, 0);
    loadA(0, a0, a1);
    xformA(0, a0, a1, 0);
    int p = 0;
    for (int kt = 0; kt < KT; ++kt) {
        __syncthreads();  // sA[p]/sW[p] ready; also frees buffer p^1 for writes
        uint4 n0, n1;
        if (kt + 1 < KT) {
            stageW(kt + 1, p ^ 1);
            loadA(kt + 1, n0, n1);   // latency overlaps MFMA below
        }
        short8 a[4], wv[4];
#pragma unroll
        for (int mt = 0; mt < 4; ++mt)
            a[mt] = *(const short8*)&sA[p][(wr * 64 + mt * 16 + l16) * 32 + q * 8];
#pragma unroll
        for (int nt = 0; nt < 4; ++nt)
            wv[nt] = *(const short8*)&sW[p][(wc * 4 + nt) * 512 + lane * 8];
#pragma unroll
        for (int nt = 0; nt < 4; ++nt)
#pragma unroll
            for (int mt = 0; mt < 4; ++mt)
                acc[mt][nt] = __builtin_amdgcn_mfma_f32_16x16x32_bf16(a[mt], wv[nt],
                                                                      acc[mt][nt], 0, 0, 0);
        if (kt + 1 < KT) xformA(kt + 1, n0, n1, p ^ 1);
        p ^= 1;
    }
#pragma unroll
    for (int nt = 0; nt < 4; ++nt) {
        int col = bn + wc * 64 + nt * 16 + l16;
#pragma unroll
        for (int mt = 0; mt < 4; ++mt) {
#pragma unroll
            for (int r = 0; r < 4; ++r) {
                int row = bm + wr * 64 + mt * 16 + q * 4 + r;
                if (row < N)
                    Hout[(size_t)row * M + col] = f2bf_rne(acc[mt][nt][r]);
            }
        }
    }
}

// ---------------- gather aggregation (half-wave pairs, wide loads) --------------
// Wave = 2 halves x 32 lanes; each half owns one edge of a pair. Each lane covers
// CPL = C/32 channels -> one dwordx4 (C=256) / dwordx2 (C=128) load fetches two
// full rows per instruction. Cross-half shfl_xor(32) reduce at the end; half-0
// lanes store panel-major.

template <int C>
__global__ __launch_bounds__(64) void gather_agg_kernel(
        const unsigned short* __restrict__ Hb, const float* __restrict__ dinv,
        const float* __restrict__ bias, const int* __restrict__ row_start,
        const int* __restrict__ csr_src, const float* __restrict__ csr_w,
        unsigned short* __restrict__ AGG, int n) {
    constexpr int CPL = C / 32;   // channels per lane (8 or 4)
    constexpr int UL = CPL / 2;   // uints per lane (4 or 2)
    int i = blockIdx.x;
    if (i >= n) return;
    int lane = threadIdx.x;
    int half = lane >> 5;
    int l32 = lane & 31;
    int c0 = l32 * CPL;
    float di = dinv[i];
    const unsigned int* base = (const unsigned int*)Hb;
    float acc[CPL] = {};
    if (half == 0) {  // self-loop + bias only once
        float w0 = di * di;
        const unsigned int* hrow = base + ((size_t)i * C >> 1) + l32 * UL;
#pragma unroll
        for (int t = 0; t < UL; ++t) {
            unsigned int u = hrow[t];
            acc[2 * t] = (bias ? bias[c0 + 2 * t] : 0.0f) + bflo(u) * w0;
            acc[2 * t + 1] = (bias ? bias[c0 + 2 * t + 1] : 0.0f) + bfhi(u) * w0;
        }
    }
    int e0 = row_start[i], e1 = row_start[i + 1];
    int e = e0;
    for (; e + 4 <= e1; e += 4) {  // halves cover edges e+half, e+2+half
        int sa = csr_src[e + half];
        int sb = csr_src[e + 2 + half];
        float wa = csr_w[e + half] * di;
        float wb = csr_w[e + 2 + half] * di;
        unsigned int ua[UL], ub[UL];
        const unsigned int* pa = base + ((size_t)sa * C >> 1) + l32 * UL;
        const unsigned int* pb = base + ((size_t)sb * C >> 1) + l32 * UL;
#pragma unroll
        for (int t = 0; t < UL; ++t) ua[t] = pa[t];
#pragma unroll
        for (int t = 0; t < UL; ++t) ub[t] = pb[t];
#pragma unroll
        for (int t = 0; t < UL; ++t) {
            acc[2 * t] += bflo(ua[t]) * wa + bflo(ub[t]) * wb;
            acc[2 * t + 1] += bfhi(ua[t]) * wa + bfhi(ub[t]) * wb;
        }
    }
    for (; e + 2 <= e1; e += 2) {  // edge pair
        int s = csr_src[e + half];
        float w = csr_w[e + half] * di;
        const unsigned int* p = base + ((size_t)s * C >> 1) + l32 * UL;
#pragma unroll
        for (int t = 0; t < UL; ++t) {
            unsigned int u = p[t];
            acc[2 * t] += bflo(u) * w;
            acc[2 * t + 1] += bfhi(u) * w;
        }
    }
    if (e < e1) {  // single tail edge: half 1 contributes weight 0
        int s = csr_src[e];
        float w = (half == 0) ? csr_w[e] * di : 0.0f;
        const unsigned int* p = base + ((size_t)s * C >> 1) + l32 * UL;
#pragma unroll
        for (int t = 0; t < UL; ++t) {
            unsigned int u = p[t];
            acc[2 * t] += bflo(u) * w;
            acc[2 * t + 1] += bfhi(u) * w;
        }
    }
    // merge halves
#pragma unroll
    for (int k = 0; k < CPL; ++k) acc[k] += __shfl_xor(acc[k], 32, 64);
    if (half == 0) {
        unsigned int o[UL];
#pragma unroll
        for (int t = 0; t < UL; ++t)
            o[t] = (unsigned int)f2bf_rne(acc[2 * t]) |
                   ((unsigned int)f2bf_rne(acc[2 * t + 1]) << 16);
        // panel-major store: channels [c0, c0+CPL) lie within one 32-ch panel
        unsigned int* dst =
            (unsigned int*)(AGG + ((size_t)(c0 >> 5) * NPAD + i) * 32 + (c0 & 31));
#pragma unroll
        for (int t = 0; t < UL; ++t) dst[t] = o[t];
    }
}

// ---------------- batch norm stats (bf16 panel-major input) ----------------

__global__ void bn_stats_kernel(const unsigned short* __restrict__ A, float* __restrict__ sums,
                                float* __restrict__ sumsq, int n, int C) {
    int c = threadIdx.x;
    size_t cbase = (size_t)(c >> 5) * NPAD * 32 + (c & 31);
    int rpb = (n + gridDim.x - 1) / gridDim.x;
    int r0 = blockIdx.x * rpb;
    int r1 = min(n, r0 + rpb);
    float s = 0.0f, s2 = 0.0f;
    for (int r = r0; r < r1; ++r) {
        float v = bf2f(A[cbase + (size_t)r * 32]);
        s += v;
        s2 += v * v;
    }
    atomicAdd(&sums[c], s);
    atomicAdd(&sumsq[c], s2);
}

// ---------------- pooling (panel-major, BN3+relu fused) ----------------

__global__ __launch_bounds__(128) void pool_part_kernel(
        const unsigned short* __restrict__ A, const float* __restrict__ sums,
        const float* __restrict__ sumsq, const float* __restrict__ gamma,
        const float* __restrict__ beta, const int* __restrict__ gstart,
        float* __restrict__ outacc) {
    int g = blockIdx.x;
    int split = blockIdx.y;
    int c = threadIdx.x;
    size_t cbase = (size_t)(c >> 5) * NPAD * 32 + (c & 31);
    int r0 = gstart[g], r1 = gstart[g + 1];
    float sc, sh;
    bn_coeff(sums, sumsq, gamma, beta, c, sc, sh);
    float s = 0.0f;
    for (int r = r0 + split; r < r1; r += POOL_SPLITS) {
        float v = bf2f(A[cbase + (size_t)r * 32]);
        s += fmaxf(v * sc + sh, 0.0f);
    }
    atomicAdd(&outacc[g * 128 + c], s);
}

__global__ void pool_fin_kernel(const float* __restrict__ outacc,
                                const int* __restrict__ gstart, float* __restrict__ out) {
    int idx = blockIdx.x * blockDim.x + threadIdx.x;
    if (idx >= NUM_GRAPHS * 128) return;
    int g = idx >> 7;
    float cnt = (float)(gstart[g + 1] - gstart[g]);
    out[idx] = outacc[idx] / fmaxf(cnt, 1.0f);
}

// ---------------- host driver ----------------

extern "C" void kernel_launch(void* const* d_in, const int* in_sizes, int n_in,
                              void* d_out, int out_size, void* d_ws, size_t ws_size,
                              hipStream_t stream) {
    const float* x     = (const float*)d_in[0];
    const int*   ei    = (const int*)d_in[1];
    const int*   batch = (const int*)d_in[2];
    const float* W1 = (const float*)d_in[3];
    const float* b1 = (const float*)d_in[4];
    const float* W2 = (const float*)d_in[5];
    const float* b2 = (const float*)d_in[6];
    const float* W3 = (const float*)d_in[7];
    const float* b3 = (const float*)d_in[8];
    const float* g1 = (const float*)d_in[9];
    const float* be1 = (const float*)d_in[10];
    const float* g2 = (const float*)d_in[11];
    const float* be2 = (const float*)d_in[12];
    const float* g3 = (const float*)d_in[13];
    const float* be3 = (const float*)d_in[14];
    float* out = (float*)d_out;

    const int* src = ei;
    const int* dstv = ei + N_EDGES;

    size_t off = 0;
    auto allocb = [&](size_t nbytes) {
        char* p = (char*)d_ws + off;
        off += (nbytes + 255) & ~(size_t)255;
        return p;
    };
    int*   deg_int   = (int*)allocb(N_NODES * 4);
    int*   row_start = (int*)allocb((N_NODES + 1) * 4);
    int*   rank      = (int*)allocb(N_EDGES * 4);
    int*   csr_src   = (int*)allocb(N_EDGES * 4);
    float* csr_w     = (float*)allocb(N_EDGES * 4);
    int*   gstart    = (int*)allocb((NUM_GRAPHS + 1) * 4);
    int*   spartial  = (int*)allocb(SCAN_BLOCKS * 4);
    int*   sboff     = (int*)allocb(SCAN_BLOCKS * 4);
    float* dinv      = (float*)allocb(N_NODES * 4);
    float* sums_all  = (float*)allocb((3 * 512 + NUM_GRAPHS * 128) * 4);  // stats + outacc
    float* outacc    = sums_all + 3 * 512;
    short* W1f       = (short*)allocb((size_t)128 * 256 * 2);
    short* W2f       = (short*)allocb((size_t)256 * 256 * 2);
    short* W3f       = (short*)allocb((size_t)256 * 128 * 2);
    unsigned short* Hbf  = (unsigned short*)allocb((size_t)NPAD * 256 * 2);  // row-major H
    unsigned short* bufA = (unsigned short*)allocb((size_t)NPAD * 256 * 2);  // panels
    unsigned short* Ap   = (unsigned short*)allocb((size_t)NPAD * 256 * 2);  // panels
    unsigned short* xbf  = Hbf;  // x-bf16 aliases Hbf (dead after layer-1 gather)
    (void)ws_size; (void)n_in; (void)in_sizes; (void)out_size;

    float* s1 = sums_all, *sq1 = sums_all + 256;
    float* s2 = sums_all + 512, *sq2 = sums_all + 768;
    float* s3 = sums_all + 1024, *sq3 = sums_all + 1280;

    int nb = (N_NODES + 255) / 256;

    // ---- prologue ----
    hipLaunchKernelGGL(zero_all_kernel, dim3(nb), dim3(256), 0, stream, deg_int, sums_all,
                       N_NODES, 3 * 512 + NUM_GRAPHS * 128);
    hipLaunchKernelGGL(prologue_kernel, dim3(4096), dim3(256), 0, stream, dstv, deg_int, rank,
                       x, xbf, W1, W2, W3, W1f, W2f, W3f);
    hipLaunchKernelGGL(scan_p1_kernel, dim3(SCAN_BLOCKS), dim3(256), 0, stream, deg_int,
                       spartial, N_NODES);
    hipLaunchKernelGGL(scan_p2_bounds_kernel, dim3(2), dim3(256), 0, stream, spartial, sboff,
                       row_start, batch, gstart, SCAN_BLOCKS, N_NODES, N_EDGES);
    hipLaunchKernelGGL(scan_p3_kernel, dim3(SCAN_BLOCKS), dim3(256), 0, stream, deg_int, sboff,
                       row_start, dinv, N_NODES);
    hipLaunchKernelGGL(fill_csr_kernel, dim3(FILL_CHUNKS * NSLICE), dim3(256), 0, stream, src,
                       dstv, rank, row_start, dinv, csr_src, csr_w, N_EDGES);

    int gx = NPAD / 128;  // 391

    // ---- layer 1: gather(xbf) -> Ap (panel); gemm(+b1) -> bufA (panel); stats1 ----
    hipLaunchKernelGGL((gather_agg_kernel<128>), dim3(N_NODES), dim3(64), 0, stream, xbf,
                       dinv, (const float*)nullptr, row_start, csr_src, csr_w, Ap, N_NODES);
    hipLaunchKernelGGL((gemm_lds_kernel<4, true>), dim3(gx, 2), dim3(256), 0, stream, Ap, W1f,
                       b1, bufA, N_NODES, 256);
    hipLaunchKernelGGL(bn_stats_kernel, dim3(1024), dim3(256), 0, stream, bufA, s1, sq1,
                       N_NODES, 256);

    // ---- layer 2: BN1-fused gemm(bufA) -> Hbf (row); gather(+b2) -> Ap; stats2 ----
    hipLaunchKernelGGL((gemm_bn_lds_kernel<8>), dim3(gx, 2), dim3(256), 0, stream, bufA, s1,
                       sq1, g1, be1, W2f, Hbf, N_NODES, 256);
    hipLaunchKernelGGL((gather_agg_kernel<256>), dim3(N_NODES), dim3(64), 0, stream, Hbf,
                       dinv, b2, row_start, csr_src, csr_w, Ap, N_NODES);
    hipLaunchKernelGGL(bn_stats_kernel, dim3(1024), dim3(256), 0, stream, Ap, s2, sq2,
                       N_NODES, 256);

    // ---- layer 3: BN2-fused gemm(Ap) -> Hbf (row); gather(+b3) -> bufA; stats3 ----
    hipLaunchKernelGGL((gemm_bn_lds_kernel<8>), dim3(gx, 1), dim3(256), 0, stream, Ap, s2,
                       sq2, g2, be2, W3f, Hbf, N_NODES, 128);
    hipLaunchKernelGGL((gather_agg_kernel<128>), dim3(N_NODES), dim3(64), 0, stream, Hbf,
                       dinv, b3, row_start, csr_src, csr_w, bufA, N_NODES);
    hipLaunchKernelGGL(bn_stats_kernel, dim3(1024), dim3(128), 0, stream, bufA, s3, sq3,
                       N_NODES, 128);

    // ---- pool: parallel segmented mean with BN3 apply+relu fused ----
    hipLaunchKernelGGL(pool_part_kernel, dim3(NUM_GRAPHS, POOL_SPLITS), dim3(128), 0, stream,
                       bufA, s3, sq3, g3, be3, gstart, outacc);
    hipLaunchKernelGGL(pool_fin_kernel, dim3((NUM_GRAPHS * 128 + 255) / 256), dim3(256), 0,
                       stream, outacc, gstart, out);
}

// Round 17
// 466.295 us; speedup vs baseline: 1.0371x; 1.0371x over previous
//
#include <hip/hip_runtime.h>

#define N_NODES 50000
#define N_EDGES 800000
#define NUM_GRAPHS 128
#define EPS 1e-5f
#define SCAN_BLOCKS 196          // ceil(50000/256)
#define NPAD 50048               // 391 * 128 (row-tile padded node count)
#define POOL_SPLITS 16
#define INV_N (1.0f / 50000.0f)
#define NSLICE 8
#define SLICE_SZ 6250            // N_NODES / NSLICE
#define FILL_CHUNKS 256
#define FILL_CHUNK 3125          // N_EDGES / FILL_CHUNKS

typedef __attribute__((ext_vector_type(8))) short short8;
typedef __attribute__((ext_vector_type(4))) float floatx4;
typedef __attribute__((ext_vector_type(4))) unsigned short ushort4v;

__device__ __forceinline__ unsigned short f2bf_rne(float f) {
    unsigned int u = __float_as_uint(f);
    u += 0x7FFF + ((u >> 16) & 1);
    return (unsigned short)(u >> 16);
}
__device__ __forceinline__ float bf2f(unsigned short h) {
    return __uint_as_float(((unsigned int)h) << 16);
}
__device__ __forceinline__ float bflo(unsigned int u) { return __uint_as_float(u << 16); }
__device__ __forceinline__ float bfhi(unsigned int u) {
    return __uint_as_float(u & 0xFFFF0000u);
}

// async global->LDS, 16B per lane
__device__ __forceinline__ void gload16(const void* g, void* l) {
#if __has_builtin(__builtin_amdgcn_global_load_lds)
    __builtin_amdgcn_global_load_lds(
        reinterpret_cast<const __attribute__((address_space(1))) unsigned int*>(
            reinterpret_cast<unsigned long long>(g)),
        reinterpret_cast<__attribute__((address_space(3))) unsigned int*>(
            reinterpret_cast<unsigned long long>(l)),
        16, 0, 0);
#else
    *(uint4*)l = *(const uint4*)g;
#endif
}

// ---------------- fused zero (deg ints + stats/pool floats) ----------------

__global__ void zero_all_kernel(int* deg, float* f, int nInt, int nF) {
    int i = blockIdx.x * blockDim.x + threadIdx.x;
    if (i < nInt) deg[i] = 0;
    if (i < nF) f[i] = 0.0f;
}

// ---------------- W packing helper (bf16 only, fragment order) ----------------

__device__ __forceinline__ void wpack_one(const float* __restrict__ W, short* __restrict__ Wf,
                                          int K, int M, int t) {
    int KT = K >> 5, MT = M >> 4;
    if (t >= KT * MT * 64) return;
    int lane = t & 63, chunk = t >> 6;
    int kt = chunk / MT, nt = chunk % MT;
    int q = lane >> 4, m = lane & 15;
    int n = nt * 16 + m;
    short* op = Wf + ((size_t)(kt * MT + nt)) * 512 + lane * 8;
#pragma unroll
    for (int j = 0; j < 8; ++j)
        op[j] = (short)f2bf_rne(W[(size_t)(kt * 32 + q * 8 + j) * M + n]);
}

// ---------------- fused prologue: count_deg+rank | wpack x3 | x->bf16 ----------

__global__ __launch_bounds__(256) void prologue_kernel(
        const int* __restrict__ dst, int* deg, int* __restrict__ rank,
        const float* __restrict__ x, unsigned short* __restrict__ xbf,
        const float* __restrict__ W1, const float* __restrict__ W2,
        const float* __restrict__ W3, short* W1f, short* W2f, short* W3f) {
    int b = blockIdx.x;
    if (b < 2048) {
        int i = b * 256 + threadIdx.x;
        const int stride = 2048 * 256;
        for (; i < N_EDGES; i += stride) rank[i] = atomicAdd(&deg[dst[i]], 1);
    } else if (b < 2112) {
        int bb = b - 2048;
        if (bb < 16) wpack_one(W1, W1f, 128, 256, bb * 256 + threadIdx.x);
        else if (bb < 48) wpack_one(W2, W2f, 256, 256, (bb - 16) * 256 + threadIdx.x);
        else wpack_one(W3, W3f, 256, 128, (bb - 48) * 256 + threadIdx.x);
    } else {
        const int n4 = N_NODES * 128 / 4;
        int i = (b - 2112) * 256 + threadIdx.x;
        const int stride = 1984 * 256;
        for (; i < n4; i += stride) {
            float4 v = ((const float4*)x)[i];
            ushort4v o = {f2bf_rne(v.x), f2bf_rne(v.y), f2bf_rne(v.z), f2bf_rne(v.w)};
            ((ushort4v*)xbf)[i] = o;
        }
    }
}

// ---------------- scan phases ----------------

__global__ __launch_bounds__(256) void scan_p1_kernel(const int* __restrict__ deg,
                                                      int* __restrict__ partial, int n) {
    __shared__ int red[256];
    int tid = threadIdx.x;
    int i = blockIdx.x * 256 + tid;
    red[tid] = (i < n) ? deg[i] : 0;
    __syncthreads();
#pragma unroll
    for (int s = 128; s > 0; s >>= 1) {
        if (tid < s) red[tid] += red[tid + s];
        __syncthreads();
    }
    if (tid == 0) partial[blockIdx.x] = red[0];
}

// block 0: exclusive scan of block partials; block 1: graph bounds (fused)
__global__ __launch_bounds__(256) void scan_p2_bounds_kernel(
        const int* __restrict__ partial, int* __restrict__ block_off,
        int* __restrict__ row_start, const int* __restrict__ batch,
        int* __restrict__ gstart, int nb, int n, int E) {
    if (blockIdx.x == 1) {
        int g = threadIdx.x;
        if (g > NUM_GRAPHS) return;
        int lo = 0, hi = n;
        while (lo < hi) {
            int mid = (lo + hi) >> 1;
            if (batch[mid] < g) lo = mid + 1; else hi = mid;
        }
        gstart[g] = lo;
        return;
    }
    __shared__ int s[256];
    int tid = threadIdx.x;
    int v = (tid < nb) ? partial[tid] : 0;
    s[tid] = v;
    __syncthreads();
#pragma unroll
    for (int off = 1; off < 256; off <<= 1) {
        int t = (tid >= off) ? s[tid - off] : 0;
        __syncthreads();
        s[tid] += t;
        __syncthreads();
    }
    if (tid < nb) block_off[tid] = s[tid] - v;
    if (tid == 0) row_start[n] = E;
}

// exclusive scan -> row_start; also dinv = rsqrt(deg+1) (fused)
__global__ __launch_bounds__(256) void scan_p3_kernel(const int* __restrict__ deg,
                                                      const int* __restrict__ block_off,
                                                      int* __restrict__ row_start,
                                                      float* __restrict__ dinv, int n) {
    __shared__ int s[256];
    int tid = threadIdx.x;
    int i = blockIdx.x * 256 + tid;
    int v = (i < n) ? deg[i] : 0;
    s[tid] = v;
    __syncthreads();
#pragma unroll
    for (int off = 1; off < 256; off <<= 1) {
        int t = (tid >= off) ? s[tid - off] : 0;
        __syncthreads();
        s[tid] += t;
        __syncthreads();
    }
    if (i < n) {
        row_start[i] = block_off[blockIdx.x] + s[tid] - v;
        dinv[i] = rsqrtf((float)(v + 1));
    }
}

// XCD-sliced fill; also stores csr_w = dinv[src] per edge.
__global__ __launch_bounds__(256) void fill_csr_kernel(
        const int* __restrict__ src, const int* __restrict__ dst,
        const int* __restrict__ rank, const int* __restrict__ row_start,
        const float* __restrict__ dinv, int* __restrict__ csr_src,
        float* __restrict__ csr_w, int E) {
    int s = blockIdx.x & (NSLICE - 1);
    int c = blockIdx.x >> 3;
    int lo = s * SLICE_SZ;
    int hi = lo + SLICE_SZ;
    int base = c * FILL_CHUNK;
    int end = min(E, base + FILL_CHUNK);
    for (int i = base + threadIdx.x; i < end; i += 256) {
        int d = dst[i];
        if (d >= lo && d < hi) {
            int sv = src[i];
            int p = row_start[d] + rank[i];
            csr_src[p] = sv;
            csr_w[p] = dinv[sv];
        }
    }
}

// ---------------- BN finalize (inline helper) ----------------

__device__ __forceinline__ void bn_coeff(const float* __restrict__ sums,
                                         const float* __restrict__ sumsq,
                                         const float* __restrict__ gamma,
                                         const float* __restrict__ beta, int c,
                                         float& sc, float& sh) {
    float mu = sums[c] * INV_N;
    float var = sumsq[c] * INV_N - mu * mu;
    float rs = rsqrtf(var + EPS);
    sc = gamma[c] * rs;
    sh = beta[c] - mu * sc;
}

// ---------------- plain double-buffered LDS MFMA GEMM (bf16 W) ----------------
// POUT: panel-major output (for next GEMM), else row-major (for gather).

template <int KT, bool POUT>
__global__ __launch_bounds__(256) void gemm_lds_kernel(
        const unsigned short* __restrict__ Ap, const short* __restrict__ Wf,
        const float* __restrict__ bias, unsigned short* __restrict__ Hout, int N, int M) {
    const int MT = M >> 4;
    __shared__ unsigned short sA[2][128 * 32];   // 2 x 8 KB
    __shared__ short sW[2][8 * 512];             // 2 x 8 KB
    int tid = threadIdx.x;
    int wave = tid >> 6, lane = tid & 63;
    int wr = wave >> 1, wc = wave & 1;
    int bm = blockIdx.x * 128;
    int bn = blockIdx.y * 128;
    int ntbb = bn >> 4;
    int q = lane >> 4, l16 = lane & 15;
    floatx4 acc[4][4] = {};

    auto stage = [&](int kt, int p) {
        const char* ab = (const char*)(Ap + ((size_t)kt * NPAD + bm) * 32);
        const char* wb = (const char*)(Wf + (size_t)(kt * MT + ntbb) * 512);
        char* sa = (char*)sA[p];
        char* sw = (char*)sW[p];
        gload16(ab + tid * 16, sa + tid * 16);
        gload16(ab + (256 + tid) * 16, sa + (256 + tid) * 16);
#pragma unroll
        for (int i = 0; i < 2; ++i)
            gload16(wb + (i * 256 + tid) * 16, sw + (i * 256 + tid) * 16);
    };

    stage(0, 0);
    int p = 0;
    for (int kt = 0; kt < KT; ++kt) {
        __syncthreads();
        if (kt + 1 < KT) stage(kt + 1, p ^ 1);
        short8 a[4], wv[4];
#pragma unroll
        for (int mt = 0; mt < 4; ++mt)
            a[mt] = *(const short8*)&sA[p][(wr * 64 + mt * 16 + l16) * 32 + q * 8];
#pragma unroll
        for (int nt = 0; nt < 4; ++nt)
            wv[nt] = *(const short8*)&sW[p][(wc * 4 + nt) * 512 + lane * 8];
#pragma unroll
        for (int nt = 0; nt < 4; ++nt)
#pragma unroll
            for (int mt = 0; mt < 4; ++mt)
                acc[mt][nt] = __builtin_amdgcn_mfma_f32_16x16x32_bf16(a[mt], wv[nt],
                                                                      acc[mt][nt], 0, 0, 0);
        p ^= 1;
    }
#pragma unroll
    for (int nt = 0; nt < 4; ++nt) {
        int col = bn + wc * 64 + nt * 16 + l16;
        float bv = bias ? bias[col] : 0.0f;
#pragma unroll
        for (int mt = 0; mt < 4; ++mt) {
#pragma unroll
            for (int r = 0; r < 4; ++r) {
                int row = bm + wr * 64 + mt * 16 + q * 4 + r;
                if (row < N) {
                    unsigned short v = f2bf_rne(acc[mt][nt][r] + bv);
                    if constexpr (POUT)
                        Hout[((size_t)(col >> 5) * NPAD + row) * 32 + (col & 31)] = v;
                    else
                        Hout[(size_t)row * M + col] = v;
                }
            }
        }
    }
}

// ---------------- BN-fused GEMM: H = relu(bn(A)) @ W, row-major bf16 out ---------

template <int KT>
__global__ __launch_bounds__(256) void gemm_bn_lds_kernel(
        const unsigned short* __restrict__ Abuf, const float* __restrict__ sums,
        const float* __restrict__ sumsq, const float* __restrict__ gamma,
        const float* __restrict__ beta, const short* __restrict__ Wf,
        unsigned short* __restrict__ Hout, int N, int M) {
    const int MT = M >> 4;
    __shared__ unsigned short sA[2][128 * 32];   // 2 x 8 KB
    __shared__ short sW[2][8 * 512];             // 2 x 8 KB
    __shared__ float scs[KT * 32], shs[KT * 32]; // 2 KB
    int tid = threadIdx.x;
    int wave = tid >> 6, lane = tid & 63;
    int wr = wave >> 1, wc = wave & 1;
    int bm = blockIdx.x * 128;
    int bn = blockIdx.y * 128;
    int ntbb = bn >> 4;
    int q = lane >> 4, l16 = lane & 15;

    if (tid < KT * 32) {
        float sc, sh;
        bn_coeff(sums, sumsq, gamma, beta, tid, sc, sh);
        scs[tid] = sc;
        shs[tid] = sh;
    }
    __syncthreads();

    int arow = tid >> 1;          // 0..127 (tile row)
    int acb = (tid & 1) * 16;     // channel base within 32-panel

    auto stageW = [&](int kt, int p) {
        const char* wb = (const char*)(Wf + (size_t)(kt * MT + ntbb) * 512);
        char* sw = (char*)sW[p];
#pragma unroll
        for (int i = 0; i < 2; ++i)
            gload16(wb + (i * 256 + tid) * 16, sw + (i * 256 + tid) * 16);
    };
    auto loadA = [&](int kt, uint4& r0, uint4& r1) {
        const unsigned short* ptr = Abuf + ((size_t)kt * NPAD + bm + arow) * 32 + acb;
        r0 = *(const uint4*)ptr;
        r1 = *(const uint4*)(ptr + 8);
    };
    auto xformA = [&](int kt, uint4 r0, uint4 r1, int p) {
        unsigned int in[8] = {r0.x, r0.y, r0.z, r0.w, r1.x, r1.y, r1.z, r1.w};
        unsigned int ow[8];
#pragma unroll
        for (int u = 0; u < 8; ++u) {
            int cb = kt * 32 + acb + 2 * u;
            float a = fmaxf(bflo(in[u]) * scs[cb] + shs[cb], 0.0f);
            float b = fmaxf(bfhi(in[u]) * scs[cb + 1] + shs[cb + 1], 0.0f);
            ow[u] = (unsigned int)f2bf_rne(a) | ((unsigned int)f2bf_rne(b) << 16);
        }
        uint4* d = (uint4*)&sA[p][(size_t)arow * 32 + acb];
        d[0] = make_uint4(ow[0], ow[1], ow[2], ow[3]);
        d[1] = make_uint4(ow[4], ow[5], ow[6], ow[7]);
    };

    floatx4 acc[4][4] = {};
    uint4 a0, a1;
    stageW(0, 0);
    loadA(0, a0, a1);
    xformA(0, a0, a1, 0);
    int p = 0;
    for (int kt = 0; kt < KT; ++kt) {
        __syncthreads();  // sA[p]/sW[p] ready; also frees buffer p^1 for writes
        uint4 n0, n1;
        if (kt + 1 < KT) {
            stageW(kt + 1, p ^ 1);
            loadA(kt + 1, n0, n1);   // latency overlaps MFMA below
        }
        short8 a[4], wv[4];
#pragma unroll
        for (int mt = 0; mt < 4; ++mt)
            a[mt] = *(const short8*)&sA[p][(wr * 64 + mt * 16 + l16) * 32 + q * 8];
#pragma unroll
        for (int nt = 0; nt < 4; ++nt)
            wv[nt] = *(const short8*)&sW[p][(wc * 4 + nt) * 512 + lane * 8];
#pragma unroll
        for (int nt = 0; nt < 4; ++nt)
#pragma unroll
            for (int mt = 0; mt < 4; ++mt)
                acc[mt][nt] = __builtin_amdgcn_mfma_f32_16x16x32_bf16(a[mt], wv[nt],
                                                                      acc[mt][nt], 0, 0, 0);
        if (kt + 1 < KT) xformA(kt + 1, n0, n1, p ^ 1);
        p ^= 1;
    }
#pragma unroll
    for (int nt = 0; nt < 4; ++nt) {
        int col = bn + wc * 64 + nt * 16 + l16;
#pragma unroll
        for (int mt = 0; mt < 4; ++mt) {
#pragma unroll
            for (int r = 0; r < 4; ++r) {
                int row = bm + wr * 64 + mt * 16 + q * 4 + r;
                if (row < N)
                    Hout[(size_t)row * M + col] = f2bf_rne(acc[mt][nt][r]);
            }
        }
    }
}

// ---------------- gather aggregation (CSR by dst, bf16 in, panel-major out) ------

template <int C>
__global__ __launch_bounds__(64) void gather_agg_kernel(
        const unsigned short* __restrict__ Hb, const float* __restrict__ dinv,
        const float* __restrict__ bias, const int* __restrict__ row_start,
        const int* __restrict__ csr_src, const float* __restrict__ csr_w,
        unsigned short* __restrict__ AGG, int n) {
    constexpr int V = C / 64;  // channels per lane (2 or 4)
    constexpr int U = V / 2;   // packed uints per lane
    int i = blockIdx.x;
    if (i >= n) return;
    int lane = threadIdx.x;
    float di = dinv[i];
    float w0 = di * di;
    const unsigned int* base = (const unsigned int*)Hb;
    float acc[V];
    {
        const unsigned int* hrow = base + ((size_t)i * C >> 1) + lane * U;
#pragma unroll
        for (int t = 0; t < U; ++t) {
            unsigned int u = hrow[t];
            acc[2 * t] = (bias ? bias[lane * V + 2 * t] : 0.0f) + bflo(u) * w0;
            acc[2 * t + 1] = (bias ? bias[lane * V + 2 * t + 1] : 0.0f) + bfhi(u) * w0;
        }
    }
    int e0 = row_start[i], e1 = row_start[i + 1];
    int e = e0;
    for (; e + 4 <= e1; e += 4) {
        int s[4];
        float w[4];
#pragma unroll
        for (int j = 0; j < 4; ++j) {
            s[j] = __builtin_amdgcn_readfirstlane(csr_src[e + j]);
            w[j] = csr_w[e + j] * di;
        }
        unsigned int u[4][U];
#pragma unroll
        for (int j = 0; j < 4; ++j) {
            const unsigned int* p = base + ((size_t)s[j] * C >> 1) + lane * U;
#pragma unroll
            for (int t = 0; t < U; ++t) u[j][t] = p[t];
        }
#pragma unroll
        for (int t = 0; t < U; ++t) {
#pragma unroll
            for (int j = 0; j < 4; ++j) {
                acc[2 * t] += bflo(u[j][t]) * w[j];
                acc[2 * t + 1] += bfhi(u[j][t]) * w[j];
            }
        }
    }
    for (; e < e1; ++e) {
        int s = __builtin_amdgcn_readfirstlane(csr_src[e]);
        float w = csr_w[e] * di;
        const unsigned int* srow = base + ((size_t)s * C >> 1) + lane * U;
#pragma unroll
        for (int t = 0; t < U; ++t) {
            unsigned int uu = srow[t];
            acc[2 * t] += bflo(uu) * w;
            acc[2 * t + 1] += bfhi(uu) * w;
        }
    }
    // panel-major output
#pragma unroll
    for (int t = 0; t < U; ++t) {
        int c = lane * V + 2 * t;
        unsigned int o = (unsigned int)f2bf_rne(acc[2 * t]) |
                         ((unsigned int)f2bf_rne(acc[2 * t + 1]) << 16);
        *(unsigned int*)(AGG + ((size_t)(c >> 5) * NPAD + i) * 32 + (c & 31)) = o;
    }
}

// ---------------- batch norm stats (bf16 panel-major input) ----------------

__global__ void bn_stats_kernel(const unsigned short* __restrict__ A, float* __restrict__ sums,
                                float* __restrict__ sumsq, int n, int C) {
    int c = threadIdx.x;
    size_t cbase = (size_t)(c >> 5) * NPAD * 32 + (c & 31);
    int rpb = (n + gridDim.x - 1) / gridDim.x;
    int r0 = blockIdx.x * rpb;
    int r1 = min(n, r0 + rpb);
    float s = 0.0f, s2 = 0.0f;
    for (int r = r0; r < r1; ++r) {
        float v = bf2f(A[cbase + (size_t)r * 32]);
        s += v;
        s2 += v * v;
    }
    atomicAdd(&sums[c], s);
    atomicAdd(&sumsq[c], s2);
}

// ---------------- pooling (panel-major, BN3+relu fused) ----------------

__global__ __launch_bounds__(128) void pool_part_kernel(
        const unsigned short* __restrict__ A, const float* __restrict__ sums,
        const float* __restrict__ sumsq, const float* __restrict__ gamma,
        const float* __restrict__ beta, const int* __restrict__ gstart,
        float* __restrict__ outacc) {
    int g = blockIdx.x;
    int split = blockIdx.y;
    int c = threadIdx.x;
    size_t cbase = (size_t)(c >> 5) * NPAD * 32 + (c & 31);
    int r0 = gstart[g], r1 = gstart[g + 1];
    float sc, sh;
    bn_coeff(sums, sumsq, gamma, beta, c, sc, sh);
    float s = 0.0f;
    for (int r = r0 + split; r < r1; r += POOL_SPLITS) {
        float v = bf2f(A[cbase + (size_t)r * 32]);
        s += fmaxf(v * sc + sh, 0.0f);
    }
    atomicAdd(&outacc[g * 128 + c], s);
}

__global__ void pool_fin_kernel(const float* __restrict__ outacc,
                                const int* __restrict__ gstart, float* __restrict__ out) {
    int idx = blockIdx.x * blockDim.x + threadIdx.x;
    if (idx >= NUM_GRAPHS * 128) return;
    int g = idx >> 7;
    float cnt = (float)(gstart[g + 1] - gstart[g]);
    out[idx] = outacc[idx] / fmaxf(cnt, 1.0f);
}

// ---------------- host driver ----------------

extern "C" void kernel_launch(void* const* d_in, const int* in_sizes, int n_in,
                              void* d_out, int out_size, void* d_ws, size_t ws_size,
                              hipStream_t stream) {
    const float* x     = (const float*)d_in[0];
    const int*   ei    = (const int*)d_in[1];
    const int*   batch = (const int*)d_in[2];
    const float* W1 = (const float*)d_in[3];
    const float* b1 = (const float*)d_in[4];
    const float* W2 = (const float*)d_in[5];
    const float* b2 = (const float*)d_in[6];
    const float* W3 = (const float*)d_in[7];
    const float* b3 = (const float*)d_in[8];
    const float* g1 = (const float*)d_in[9];
    const float* be1 = (const float*)d_in[10];
    const float* g2 = (const float*)d_in[11];
    const float* be2 = (const float*)d_in[12];
    const float* g3 = (const float*)d_in[13];
    const float* be3 = (const float*)d_in[14];
    float* out = (float*)d_out;

    const int* src = ei;
    const int* dstv = ei + N_EDGES;

    size_t off = 0;
    auto allocb = [&](size_t nbytes) {
        char* p = (char*)d_ws + off;
        off += (nbytes + 255) & ~(size_t)255;
        return p;
    };
    int*   deg_int   = (int*)allocb(N_NODES * 4);
    int*   row_start = (int*)allocb((N_NODES + 1) * 4);
    int*   rank      = (int*)allocb(N_EDGES * 4);
    int*   csr_src   = (int*)allocb(N_EDGES * 4);
    float* csr_w     = (float*)allocb(N_EDGES * 4);
    int*   gstart    = (int*)allocb((NUM_GRAPHS + 1) * 4);
    int*   spartial  = (int*)allocb(SCAN_BLOCKS * 4);
    int*   sboff     = (int*)allocb(SCAN_BLOCKS * 4);
    float* dinv      = (float*)allocb(N_NODES * 4);
    float* sums_all  = (float*)allocb((3 * 512 + NUM_GRAPHS * 128) * 4);  // stats + outacc
    float* outacc    = sums_all + 3 * 512;
    short* W1f       = (short*)allocb((size_t)128 * 256 * 2);
    short* W2f       = (short*)allocb((size_t)256 * 256 * 2);
    short* W3f       = (short*)allocb((size_t)256 * 128 * 2);
    unsigned short* Hbf  = (unsigned short*)allocb((size_t)NPAD * 256 * 2);  // row-major H
    unsigned short* bufA = (unsigned short*)allocb((size_t)NPAD * 256 * 2);  // panels
    unsigned short* Ap   = (unsigned short*)allocb((size_t)NPAD * 256 * 2);  // panels
    unsigned short* xbf  = Hbf;  // x-bf16 aliases Hbf (dead after layer-1 gather)
    (void)ws_size; (void)n_in; (void)in_sizes; (void)out_size;

    float* s1 = sums_all, *sq1 = sums_all + 256;
    float* s2 = sums_all + 512, *sq2 = sums_all + 768;
    float* s3 = sums_all + 1024, *sq3 = sums_all + 1280;

    int nb = (N_NODES + 255) / 256;

    // ---- prologue ----
    hipLaunchKernelGGL(zero_all_kernel, dim3(nb), dim3(256), 0, stream, deg_int, sums_all,
                       N_NODES, 3 * 512 + NUM_GRAPHS * 128);
    hipLaunchKernelGGL(prologue_kernel, dim3(4096), dim3(256), 0, stream, dstv, deg_int, rank,
                       x, xbf, W1, W2, W3, W1f, W2f, W3f);
    hipLaunchKernelGGL(scan_p1_kernel, dim3(SCAN_BLOCKS), dim3(256), 0, stream, deg_int,
                       spartial, N_NODES);
    hipLaunchKernelGGL(scan_p2_bounds_kernel, dim3(2), dim3(256), 0, stream, spartial, sboff,
                       row_start, batch, gstart, SCAN_BLOCKS, N_NODES, N_EDGES);
    hipLaunchKernelGGL(scan_p3_kernel, dim3(SCAN_BLOCKS), dim3(256), 0, stream, deg_int, sboff,
                       row_start, dinv, N_NODES);
    hipLaunchKernelGGL(fill_csr_kernel, dim3(FILL_CHUNKS * NSLICE), dim3(256), 0, stream, src,
                       dstv, rank, row_start, dinv, csr_src, csr_w, N_EDGES);

    int gx = NPAD / 128;  // 391

    // ---- layer 1: gather(xbf) -> Ap (panel); gemm(+b1) -> bufA (panel); stats1 ----
    hipLaunchKernelGGL((gather_agg_kernel<128>), dim3(N_NODES), dim3(64), 0, stream, xbf,
                       dinv, (const float*)nullptr, row_start, csr_src, csr_w, Ap, N_NODES);
    hipLaunchKernelGGL((gemm_lds_kernel<4, true>), dim3(gx, 2), dim3(256), 0, stream, Ap, W1f,
                       b1, bufA, N_NODES, 256);
    hipLaunchKernelGGL(bn_stats_kernel, dim3(1024), dim3(256), 0, stream, bufA, s1, sq1,
                       N_NODES, 256);

    // ---- layer 2: BN1-fused gemm(bufA) -> Hbf (row); gather(+b2) -> Ap; stats2 ----
    hipLaunchKernelGGL((gemm_bn_lds_kernel<8>), dim3(gx, 2), dim3(256), 0, stream, bufA, s1,
                       sq1, g1, be1, W2f, Hbf, N_NODES, 256);
    hipLaunchKernelGGL((gather_agg_kernel<256>), dim3(N_NODES), dim3(64), 0, stream, Hbf,
                       dinv, b2, row_start, csr_src, csr_w, Ap, N_NODES);
    hipLaunchKernelGGL(bn_stats_kernel, dim3(1024), dim3(256), 0, stream, Ap, s2, sq2,
                       N_NODES, 256);

    // ---- layer 3: BN2-fused gemm(Ap) -> Hbf (row); gather(+b3) -> bufA; stats3 ----
    hipLaunchKernelGGL((gemm_bn_lds_kernel<8>), dim3(gx, 1), dim3(256), 0, stream, Ap, s2,
                       sq2, g2, be2, W3f, Hbf, N_NODES, 128);
    hipLaunchKernelGGL((gather_agg_kernel<128>), dim3(N_NODES), dim3(64), 0, stream, Hbf,
                       dinv, b3, row_start, csr_src, csr_w, bufA, N_NODES);
    hipLaunchKernelGGL(bn_stats_kernel, dim3(1024), dim3(128), 0, stream, bufA, s3, sq3,
                       N_NODES, 128);

    // ---- pool: parallel segmented mean with BN3 apply+relu fused ----
    hipLaunchKernelGGL(pool_part_kernel, dim3(NUM_GRAPHS, POOL_SPLITS), dim3(128), 0, stream,
                       bufA, s3, sq3, g3, be3, gstart, outacc);
    hipLaunchKernelGGL(pool_fin_kernel, dim3((NUM_GRAPHS * 128 + 255) / 256), dim3(256), 0,
                       stream, outacc, gstart, out);
}